// Round 7
// baseline (74.399 us; speedup 1.0000x reference)
//
#include <hip/hip_runtime.h>

typedef _Float16 f16;
typedef __attribute__((ext_vector_type(8))) _Float16 f16x8;
typedef __attribute__((ext_vector_type(4))) float f32x4;

#define HWB 16384

// K layout (both GEMMs): k = kk*64 + c, 18 k-steps of 32 (ch-half in {0,1}).
// A-frag packs: lane l of k-step t, M-tile m holds W[o = m*16 + (l&15)]
//               [c = (t&1)*32 + (l>>4)*8 + j], kk = t>>1.
// wdef_ap: [t(18)][m(4)][lane(64)][j(8)] f16 = 73728 B
// woff_ap: [t(18)][m(2)][lane(64)][j(8)] f16 = 36864 B (o>=18 zero)

__global__ void k_prep(const float* __restrict__ w_off,
                       const float* __restrict__ w_def,
                       f16* __restrict__ wdef_ap,
                       f16* __restrict__ woff_ap) {
    int i = blockIdx.x * 256 + threadIdx.x;
    if (i < 36864) {
        int j = i & 7, l = (i >> 3) & 63, m = (i >> 9) & 3, t = i >> 11;
        int kk = t >> 1, ch = t & 1;
        int o = m * 16 + (l & 15);
        int c = ch * 32 + (l >> 4) * 8 + j;
        wdef_ap[i] = (f16)w_def[o * 576 + c * 9 + kk];
    } else if (i < 36864 + 18432) {
        int i2 = i - 36864;
        int j = i2 & 7, l = (i2 >> 3) & 63, m = (i2 >> 9) & 1, t = i2 >> 10;
        int kk = t >> 1, ch = t & 1;
        int o = m * 16 + (l & 15);
        int c = ch * 32 + (l >> 4) * 8 + j;
        woff_ap[i2] = (f16)((o < 18) ? w_off[o * 576 + c * 9 + kk] : 0.f);
    }
}

// NCHW f32 -> NHWC f16.
__global__ void k_xpose(const float* __restrict__ x, f16* __restrict__ xt) {
    int p = blockIdx.x * 256 + threadIdx.x;
    int b = p >> 14, hw = p & 16383;
    const float* xb = x + (size_t)b * 64 * HWB + hw;
    f16x8 r[8];
    #pragma unroll
    for (int c = 0; c < 64; ++c) r[c >> 3][c & 7] = (f16)xb[(size_t)c * HWB];
    f16* ob = xt + (size_t)p * 64;
    #pragma unroll
    for (int q = 0; q < 8; ++q) *(f16x8*)(ob + q * 8) = r[q];
}

// Block: 256 thr = 4 waves = 2 px-groups (16 px) x 2 ch-halves. 32 px/block.
// Each wave runs 9 k-steps (its ch-half); partials summed via LDS.
__launch_bounds__(256, 8)
__global__ void k_fused(const f16* __restrict__ xt,      // NHWC f16 slice
                        const f16* __restrict__ woff_ap,
                        const float* __restrict__ b_off,
                        const f16* __restrict__ wdef_ap,
                        const float* __restrict__ b_def,
                        float* __restrict__ out, int bstart) {
    __shared__ float redbuf[16][128];            // [elem][pxg*64+lane], 8 KB
    __shared__ float offsm[18 * 33];             // [o][px_in_block]

    int nwg = gridDim.x;
    int bid = blockIdx.x;
    int sb = (bid & 7) * (nwg >> 3) + (bid >> 3);   // bijective XCD swizzle
    int bl = sb >> 9, h = (sb >> 2) & 127, quarter = sb & 3;
    int b = bstart + bl;
    int tid = threadIdx.x;
    int lane = tid & 63, wv = tid >> 6;
    int pxg = wv & 1, chh = wv >> 1;
    int l15 = lane & 15, g = lane >> 4;
    int pxl = pxg * 16 + l15;                    // px within block's 32
    int pxb = quarter * 32 + pxl;                // global col
    int rlane = pxg * 64 + lane;

    const f16* xb = xt + (size_t)bl * HWB * 64;
    unsigned cg = (unsigned)(g * 8);             // lane-group channel offset
    unsigned ch32 = (unsigned)(chh * 32);        // wave's channel half

    // ---------------- phase 0: 3x3 offset conv (partial over ch-half) ----
    f32x4 oacc[2];
    {
        f32x4 z = {0.f, 0.f, 0.f, 0.f};
        oacc[0] = z; oacc[1] = z;
    }
    f16x8 zb = {};
    #pragma unroll
    for (int kk = 0; kk < 9; ++kk) {
        int ky = kk / 3 - 1, kx = kk - (kk / 3) * 3 - 1;
        int yy = h + ky;
        int xx = pxb + kx;
        bool valid = ((unsigned)yy < 128u) && ((unsigned)xx < 128u);
        int yyc = min(max(yy, 0), 127), xxc = min(max(xx, 0), 127);
        unsigned ab = (unsigned)(yyc * 128 + xxc) * 64u + cg + ch32;
        int t = kk * 2 + chh;
        f16x8 B = *(const f16x8*)(xb + ab);
        B = valid ? B : zb;
        #pragma unroll
        for (int m = 0; m < 2; ++m) {
            f16x8 A = *(const f16x8*)(woff_ap + ((size_t)(t * 2 + m) * 64 + lane) * 8);
            oacc[m] = __builtin_amdgcn_mfma_f32_16x16x32_f16(A, B, oacc[m], 0, 0, 0);
        }
    }
    if (chh == 1) {
        #pragma unroll
        for (int m = 0; m < 2; ++m)
            #pragma unroll
            for (int r = 0; r < 4; ++r) redbuf[m * 4 + r][rlane] = oacc[m][r];
    }
    __syncthreads();
    if (chh == 0) {
        #pragma unroll
        for (int m = 0; m < 2; ++m)
            #pragma unroll
            for (int r = 0; r < 4; ++r) {
                int o = m * 16 + g * 4 + r;
                if (o < 18) {
                    float v = oacc[m][r] + redbuf[m * 4 + r][rlane] + b_off[o];
                    offsm[o * 33 + pxl] = fminf(fmaxf(v, -1.f), 1.f);
                }
            }
    }
    __syncthreads();

    // ---------------- phase 1: deformable conv (partial over ch-half) ----
    f32x4 acc[4];
    {
        f32x4 z = {0.f, 0.f, 0.f, 0.f};
        acc[0] = z; acc[1] = z; acc[2] = z; acc[3] = z;
    }
    #pragma unroll
    for (int kk = 0; kk < 9; ++kk) {
        float dy = offsm[(2 * kk) * 33 + pxl];
        float dx = offsm[(2 * kk + 1) * 33 + pxl];
        int ky = kk / 3 - 1, kx = kk - (kk / 3) * 3 - 1;
        float py = (float)(h + ky) + dy;
        float pxf = (float)(pxb + kx) + dx;
        float y0f = floorf(py), x0f = floorf(pxf);
        float ly = py - y0f, lx = pxf - x0f;
        int y0 = (int)y0f, x0 = (int)x0f;
        float vy0 = ((unsigned)y0 < 128u) ? 1.f : 0.f;
        float vy1 = ((unsigned)(y0 + 1) < 128u) ? 1.f : 0.f;
        float vx0 = ((unsigned)x0 < 128u) ? 1.f : 0.f;
        float vx1 = ((unsigned)(x0 + 1) < 128u) ? 1.f : 0.f;
        f16 w0 = (f16)((1.f - ly) * (1.f - lx) * vy0 * vx0);
        f16 w1 = (f16)((1.f - ly) * lx * vy0 * vx1);
        f16 w2 = (f16)(ly * (1.f - lx) * vy1 * vx0);
        f16 w3 = (f16)(ly * lx * vy1 * vx1);
        int yc0 = min(max(y0, 0), 127), yc1 = min(max(y0 + 1, 0), 127);
        int xc0 = min(max(x0, 0), 127), xc1 = min(max(x0 + 1, 0), 127);
        unsigned ab  = (unsigned)(yc0 * 128 + xc0) * 64u + cg + ch32;
        unsigned adx = (unsigned)(xc1 - xc0) * 64u;      // 0 or 64
        unsigned ady = (unsigned)(yc1 - yc0) * 8192u;    // 0 or 128*64

        int t = kk * 2 + chh;
        f16x8 c00 = *(const f16x8*)(xb + ab);
        f16x8 c01 = *(const f16x8*)(xb + ab + adx);
        f16x8 c10 = *(const f16x8*)(xb + ab + ady);
        f16x8 c11 = *(const f16x8*)(xb + ab + ady + adx);
        f16x8 B = c00 * w0 + c01 * w1 + c10 * w2 + c11 * w3;
        #pragma unroll
        for (int m = 0; m < 4; ++m) {
            f16x8 A = *(const f16x8*)(wdef_ap + ((size_t)(t * 4 + m) * 64 + lane) * 8);
            acc[m] = __builtin_amdgcn_mfma_f32_16x16x32_f16(A, B, acc[m], 0, 0, 0);
        }
    }

    if (chh == 1) {
        #pragma unroll
        for (int m = 0; m < 4; ++m)
            #pragma unroll
            for (int r = 0; r < 4; ++r) redbuf[m * 4 + r][rlane] = acc[m][r];
    }
    __syncthreads();
    if (chh == 0) {
        #pragma unroll
        for (int m = 0; m < 4; ++m)
            #pragma unroll
            for (int r = 0; r < 4; ++r) {
                int o = m * 16 + g * 4 + r;
                float v = acc[m][r] + redbuf[m * 4 + r][rlane] + b_def[o];
                out[(size_t)(b * 64 + o) * HWB + h * 128 + pxb] = v;
            }
    }
}

extern "C" void kernel_launch(void* const* d_in, const int* in_sizes, int n_in,
                              void* d_out, int out_size, void* d_ws, size_t ws_size,
                              hipStream_t stream) {
    const float* x     = (const float*)d_in[0];
    const float* w_off = (const float*)d_in[1];
    const float* b_off = (const float*)d_in[2];
    const float* w_def = (const float*)d_in[3];
    const float* b_def = (const float*)d_in[4];
    float* out = (float*)d_out;

    char* wsb = (char*)d_ws;
    f16* wdef_ap = (f16*)wsb;                    // 73728 B
    f16* woff_ap = (f16*)(wsb + 73728);          // 36864 B
    f16* xt      = (f16*)(wsb + 110592);         // NHWC f16

    k_prep<<<216, 256, 0, stream>>>(w_off, w_def, wdef_ap, woff_ap);

    if (ws_size >= (size_t)110592 + 8388608) {
        // single shot: all 4 batches transposed (8.4 MB)
        k_xpose<<<256, 256, 0, stream>>>(x, xt);
        k_fused<<<2048, 256, 0, stream>>>(xt, woff_ap, b_off, wdef_ap, b_def, out, 0);
    } else {
        // batch-sliced fallback (2.1 MB slice, stream-ordered)
        for (int b = 0; b < 4; ++b) {
            k_xpose<<<64, 256, 0, stream>>>(x + (size_t)b * 64 * HWB, xt);
            k_fused<<<512, 256, 0, stream>>>(xt, woff_ap, b_off, wdef_ap, b_def, out, b);
        }
    }
}

// Round 8
// 43.728 us; speedup vs baseline: 1.7014x; 1.7014x over previous
//
#include <hip/hip_runtime.h>

typedef _Float16 f16;
typedef __attribute__((ext_vector_type(8))) _Float16 f16x8;
typedef __attribute__((ext_vector_type(4))) float f32x4;

#define HWB 16384

// K layout (both GEMMs): k = kk*64 + c, 18 k-steps of 32 (ch-half in {0,1}).
// A-frag packs: lane l of k-step t, M-tile m holds W[o = m*16 + (l&15)]
//               [c = (t&1)*32 + (l>>4)*8 + j], kk = t>>1.
// wdef_ap: [t(18)][m(4)][lane(64)][j(8)] f16 = 73728 B
// woff_ap: [t(18)][m(2)][lane(64)][j(8)] f16 = 36864 B (o>=18 zero)

__global__ void k_prep(const float* __restrict__ w_off,
                       const float* __restrict__ w_def,
                       f16* __restrict__ wdef_ap,
                       f16* __restrict__ woff_ap) {
    int i = blockIdx.x * 256 + threadIdx.x;
    if (i < 36864) {
        int j = i & 7, l = (i >> 3) & 63, m = (i >> 9) & 3, t = i >> 11;
        int kk = t >> 1, ch = t & 1;
        int o = m * 16 + (l & 15);
        int c = ch * 32 + (l >> 4) * 8 + j;
        wdef_ap[i] = (f16)w_def[o * 576 + c * 9 + kk];
    } else if (i < 36864 + 18432) {
        int i2 = i - 36864;
        int j = i2 & 7, l = (i2 >> 3) & 63, m = (i2 >> 9) & 1, t = i2 >> 10;
        int kk = t >> 1, ch = t & 1;
        int o = m * 16 + (l & 15);
        int c = ch * 32 + (l >> 4) * 8 + j;
        woff_ap[i2] = (f16)((o < 18) ? w_off[o * 576 + c * 9 + kk] : 0.f);
    }
}

// NCHW f32 -> NHWC f16.
__global__ void k_xpose(const float* __restrict__ x, f16* __restrict__ xt) {
    int p = blockIdx.x * 256 + threadIdx.x;
    int b = p >> 14, hw = p & 16383;
    const float* xb = x + (size_t)b * 64 * HWB + hw;
    f16x8 r[8];
    #pragma unroll
    for (int c = 0; c < 64; ++c) r[c >> 3][c & 7] = (f16)xb[(size_t)c * HWB];
    f16* ob = xt + (size_t)p * 64;
    #pragma unroll
    for (int q = 0; q < 8; ++q) *(f16x8*)(ob + q * 8) = r[q];
}

// Block: 256 thr = 4 waves = 2 px-groups x 2 ch-halves; 32 px per block.
// x 6-row band staged in LDS (hardtanh bounds |off|<=1 -> rows [h-2,h+3]);
// all bilinear gathers hit LDS. Cell = 128B (64ch f16); chunk XOR-swizzle
// (cc = gg ^ (cx&7)) spreads a wave's same-ch-group reads over all banks.
__launch_bounds__(256, 4)
__global__ void k_fused(const f16* __restrict__ xt,      // NHWC f16 slice
                        const f16* __restrict__ woff_ap,
                        const float* __restrict__ b_off,
                        const f16* __restrict__ wdef_ap,
                        const float* __restrict__ b_def,
                        float* __restrict__ out, int bstart) {
    __shared__ __align__(16) char band[6 * 40 * 128];    // 30720 B
    __shared__ float offsm[18 * 33];
    __shared__ float red0[8 * 128];
    float* red1 = (float*)band;                          // aliased after phase 1

    int nwg = gridDim.x;
    int bid = blockIdx.x;
    int sb = (bid & 7) * (nwg >> 3) + (bid >> 3);        // bijective XCD swizzle
    int bl = sb >> 9, h = (sb >> 2) & 127, quarter = sb & 3;
    int b = bstart + bl;
    int s = quarter * 32;                                // block px start
    int tid = threadIdx.x;
    int lane = tid & 63, wv = tid >> 6;
    int pxg = wv & 1, chh = wv >> 1;
    int l15 = lane & 15, g = lane >> 4;
    int pxl = pxg * 16 + l15;
    int pxb = s + pxl;
    int rlane = pxg * 64 + lane;

    const f16* xb = xt + (size_t)bl * HWB * 64;
    unsigned co = (unsigned)((chh * 4 + g) * 16);        // chunk offset pre-XOR

    // ---------------- stage 6-row band: rows h-2..h+3, cells s-2..s+34 ----
    for (int i = tid; i < 6 * 37 * 8; i += 256) {
        int gg = i & 7, cell = (i >> 3) % 37, r = (i >> 3) / 37;
        int y = min(max(h - 2 + r, 0), 127);
        int xg = min(max(s - 2 + cell, 0), 127);
        f16x8 v = *(const f16x8*)(xb + (size_t)((y * 128 + xg) * 64 + gg * 8));
        int cc = gg ^ (cell & 7);
        *(f16x8*)(band + (r * 40 + cell) * 128 + cc * 16) = v;
    }
    __syncthreads();

    // ---------------- phase 0: 3x3 offset conv (partial over ch-half) ----
    f32x4 oacc[2];
    {
        f32x4 z = {0.f, 0.f, 0.f, 0.f};
        oacc[0] = z; oacc[1] = z;
    }
    f16x8 zb = {};
    #pragma unroll
    for (int kk = 0; kk < 9; ++kk) {
        int ky = kk / 3 - 1, kx = kk - (kk / 3) * 3 - 1;
        int yy = h + ky, xx = pxb + kx;
        bool valid = ((unsigned)yy < 128u) && ((unsigned)xx < 128u);
        int ry = min(max(yy, 0), 127) - (h - 2);
        int cx = min(max(xx, 0), 127) - (s - 2);
        f16x8 B = *(const f16x8*)(band + (ry * 40 + cx) * 128 +
                                  (co ^ (((unsigned)cx & 7u) << 4)));
        B = valid ? B : zb;
        int t = kk * 2 + chh;
        #pragma unroll
        for (int m = 0; m < 2; ++m) {
            f16x8 A = *(const f16x8*)(woff_ap + ((size_t)(t * 2 + m) * 64 + lane) * 8);
            oacc[m] = __builtin_amdgcn_mfma_f32_16x16x32_f16(A, B, oacc[m], 0, 0, 0);
        }
    }
    if (chh == 1) {
        #pragma unroll
        for (int m = 0; m < 2; ++m)
            #pragma unroll
            for (int r = 0; r < 4; ++r) red0[(m * 4 + r) * 128 + rlane] = oacc[m][r];
    }
    __syncthreads();
    if (chh == 0) {
        #pragma unroll
        for (int m = 0; m < 2; ++m)
            #pragma unroll
            for (int r = 0; r < 4; ++r) {
                int o = m * 16 + g * 4 + r;
                if (o < 18) {
                    float v = oacc[m][r] + red0[(m * 4 + r) * 128 + rlane] + b_off[o];
                    offsm[o * 33 + pxl] = fminf(fmaxf(v, -1.f), 1.f);
                }
            }
    }
    __syncthreads();

    // ---------------- phase 1: deformable conv (partial over ch-half) ----
    f32x4 acc[4];
    {
        f32x4 z = {0.f, 0.f, 0.f, 0.f};
        acc[0] = z; acc[1] = z; acc[2] = z; acc[3] = z;
    }
    #pragma unroll
    for (int kk = 0; kk < 9; ++kk) {
        float dy = offsm[(2 * kk) * 33 + pxl];
        float dx = offsm[(2 * kk + 1) * 33 + pxl];
        int ky = kk / 3 - 1, kx = kk - (kk / 3) * 3 - 1;
        float py = (float)(h + ky) + dy;
        float pxf = (float)(pxb + kx) + dx;
        float y0f = floorf(py), x0f = floorf(pxf);
        float ly = py - y0f, lx = pxf - x0f;
        int y0 = (int)y0f, x0 = (int)x0f;
        float vy0 = ((unsigned)y0 < 128u) ? 1.f : 0.f;
        float vy1 = ((unsigned)(y0 + 1) < 128u) ? 1.f : 0.f;
        float vx0 = ((unsigned)x0 < 128u) ? 1.f : 0.f;
        float vx1 = ((unsigned)(x0 + 1) < 128u) ? 1.f : 0.f;
        f16 w0 = (f16)((1.f - ly) * (1.f - lx) * vy0 * vx0);
        f16 w1 = (f16)((1.f - ly) * lx * vy0 * vx1);
        f16 w2 = (f16)(ly * (1.f - lx) * vy1 * vx0);
        f16 w3 = (f16)(ly * lx * vy1 * vx1);
        int yc0 = min(max(y0, 0), 127), yc1 = min(max(y0 + 1, 0), 127);
        int xc0 = min(max(x0, 0), 127), xc1 = min(max(x0 + 1, 0), 127);
        int ry0 = yc0 - (h - 2), ry1 = yc1 - (h - 2);
        int cx0 = xc0 - (s - 2), cx1 = xc1 - (s - 2);
        unsigned s0 = co ^ (((unsigned)cx0 & 7u) << 4);
        unsigned s1 = co ^ (((unsigned)cx1 & 7u) << 4);
        f16x8 c00 = *(const f16x8*)(band + (ry0 * 40 + cx0) * 128 + s0);
        f16x8 c01 = *(const f16x8*)(band + (ry0 * 40 + cx1) * 128 + s1);
        f16x8 c10 = *(const f16x8*)(band + (ry1 * 40 + cx0) * 128 + s0);
        f16x8 c11 = *(const f16x8*)(band + (ry1 * 40 + cx1) * 128 + s1);
        f16x8 B = c00 * w0 + c01 * w1 + c10 * w2 + c11 * w3;
        int t = kk * 2 + chh;
        #pragma unroll
        for (int m = 0; m < 4; ++m) {
            f16x8 A = *(const f16x8*)(wdef_ap + ((size_t)(t * 4 + m) * 64 + lane) * 8);
            acc[m] = __builtin_amdgcn_mfma_f32_16x16x32_f16(A, B, acc[m], 0, 0, 0);
        }
    }

    __syncthreads();                                   // band reads done
    if (chh == 1) {
        #pragma unroll
        for (int m = 0; m < 4; ++m)
            #pragma unroll
            for (int r = 0; r < 4; ++r) red1[(m * 4 + r) * 128 + rlane] = acc[m][r];
    }
    __syncthreads();
    if (chh == 0) {
        #pragma unroll
        for (int m = 0; m < 4; ++m)
            #pragma unroll
            for (int r = 0; r < 4; ++r) {
                int o = m * 16 + g * 4 + r;
                float v = acc[m][r] + red1[(m * 4 + r) * 128 + rlane] + b_def[o];
                out[(size_t)(b * 64 + o) * HWB + h * 128 + pxb] = v;
            }
    }
}

extern "C" void kernel_launch(void* const* d_in, const int* in_sizes, int n_in,
                              void* d_out, int out_size, void* d_ws, size_t ws_size,
                              hipStream_t stream) {
    const float* x     = (const float*)d_in[0];
    const float* w_off = (const float*)d_in[1];
    const float* b_off = (const float*)d_in[2];
    const float* w_def = (const float*)d_in[3];
    const float* b_def = (const float*)d_in[4];
    float* out = (float*)d_out;

    char* wsb = (char*)d_ws;
    f16* wdef_ap = (f16*)wsb;                    // 73728 B
    f16* woff_ap = (f16*)(wsb + 73728);          // 36864 B
    f16* xt      = (f16*)(wsb + 110592);         // NHWC f16

    k_prep<<<216, 256, 0, stream>>>(w_off, w_def, wdef_ap, woff_ap);

    if (ws_size >= (size_t)110592 + 8388608) {
        // single shot: all 4 batches transposed (8.4 MB)
        k_xpose<<<256, 256, 0, stream>>>(x, xt);
        k_fused<<<2048, 256, 0, stream>>>(xt, woff_ap, b_off, wdef_ap, b_def, out, 0);
    } else {
        // batch-sliced fallback (2.1 MB slice, stream-ordered)
        for (int b = 0; b < 4; ++b) {
            k_xpose<<<64, 256, 0, stream>>>(x + (size_t)b * 64 * HWB, xt);
            k_fused<<<512, 256, 0, stream>>>(xt, woff_ap, b_off, wdef_ap, b_def, out, b);
        }
    }
}